// Round 4
// baseline (195.376 us; speedup 1.0000x reference)
//
#include <hip/hip_runtime.h>
#include <math.h>

#define Dd 32
#define Hh 256

using short8  = __attribute__((ext_vector_type(8))) short;
using floatx4 = __attribute__((ext_vector_type(4))) float;

__device__ inline unsigned short f2bf(float f) {
    union { float f; unsigned u; } v; v.f = f;
    unsigned r = (v.u + 0x7FFFu + ((v.u >> 16) & 1u)) >> 16;
    return (unsigned short)r;
}
__device__ inline float bf2f(unsigned short h) {
    union { unsigned u; float f; } v; v.u = ((unsigned)h) << 16;
    return v.f;
}

// ============================================================================
// KA: three partitions in one launch (grid.x = B/2 + 132 + 32):
//   [0, B/2):        forward layers 1-2 for one net x 4 samples (+ score head)
//   [B/2, B/2+132):  Mt precompute (kq 0..3, i 0..32)
//   [B/2+132, +32):  cW3 -> cW3t bf16 transpose-cast [1024][256]
// ============================================================================
__global__ __launch_bounds__(256) void ka_fused(
    const float* __restrict__ x,
    const float* __restrict__ sW1, const float* __restrict__ sb1,
    const float* __restrict__ sW2, const float* __restrict__ sb2,
    const float* __restrict__ sW3, const float* __restrict__ sb3,
    const float* __restrict__ cW1, const float* __restrict__ cb1,
    const float* __restrict__ cW2, const float* __restrict__ cb2,
    const float* __restrict__ cW3,
    float* __restrict__ out_score,
    unsigned short* __restrict__ T1s, unsigned short* __restrict__ T2s,
    unsigned short* __restrict__ T1c, unsigned short* __restrict__ T2c,
    unsigned short* __restrict__ H2c,
    unsigned short* __restrict__ Mt,  unsigned short* __restrict__ cW3t,
    int B)
{
    __shared__ char smem[33792];
    const int tid = threadIdx.x;
    const int bid = blockIdx.x;
    const int nfwd = B / 2;

    if (bid < nfwd) {
        // ---------------- forward: net = bid&1, samples sb..sb+3 ----------------
        const int net = bid & 1;
        const int sb  = (bid >> 1) * 4;
        float (*xT)[4]  = (float(*)[4])smem;            // [32][4]
        float (*h1t)[4] = (float(*)[4])(smem + 512);    // [256][4]
        float (*a2t)[4] = (float(*)[4])(smem + 4608);   // [256][4]

        if (tid < 128) {
            int s = tid >> 5, ii = tid & 31;
            xT[ii][s] = x[(sb + s) * Dd + ii];
        }
        __syncthreads();

        const float* W1 = net ? cW1 : sW1;  const float* b1 = net ? cb1 : sb1;
        const float* W2 = net ? cW2 : sW2;  const float* b2 = net ? cb2 : sb2;
        unsigned short* T1 = net ? T1c : T1s;
        unsigned short* T2 = net ? T2c : T2s;
        const int col = tid;

        float z[4];
        {
            float bb = b1[col];
            #pragma unroll
            for (int s = 0; s < 4; ++s) z[s] = bb;
        }
        #pragma unroll
        for (int ii = 0; ii < 32; ++ii) {
            float w = W1[ii * 256 + col];
            float4 xv = *(const float4*)xT[ii];
            z[0] += w * xv.x; z[1] += w * xv.y; z[2] += w * xv.z; z[3] += w * xv.w;
        }
        #pragma unroll
        for (int s = 0; s < 4; ++s) {
            float h = tanhf(z[s]);
            h1t[col][s] = h;
            T1[(size_t)(sb + s) * 256 + col] = f2bf(1.0f - h * h);
        }
        __syncthreads();

        {
            float bb = b2[col];
            #pragma unroll
            for (int s = 0; s < 4; ++s) z[s] = bb;
        }
        #pragma unroll 8
        for (int k = 0; k < 256; ++k) {
            float w = W2[k * 256 + col];
            float4 hv = *(const float4*)h1t[k];
            z[0] += w * hv.x; z[1] += w * hv.y; z[2] += w * hv.z; z[3] += w * hv.w;
        }
        #pragma unroll
        for (int s = 0; s < 4; ++s) {
            float h = tanhf(z[s]);
            T2[(size_t)(sb + s) * 256 + col] = f2bf(1.0f - h * h);
            if (net) H2c[(size_t)(sb + s) * 256 + col] = f2bf(h);
            else     a2t[col][s] = h;
        }
        __syncthreads();

        if (!net && tid < 128) {
            int m = tid & 31, s = tid >> 5;
            float zz = sb3[m];
            #pragma unroll 8
            for (int k = 0; k < 256; ++k)
                zz += a2t[k][s] * sW3[k * Dd + m];
            out_score[(size_t)(sb + s) * Dd + m] = zz;
        }
        return;
    }

    if (bid < nfwd + 132) {
        // ---------------- Mt precompute ----------------
        const int pb = bid - nfwd;
        const int kq = pb & 3;        // k quarter
        const int i  = pb >> 2;       // 0..32
        float (*W1t)[36] = (float(*)[36])smem;   // [64][36]

        const float *W1, *W2, *C3;
        int cstride, coff;
        if (i == 0) { W1 = sW1; W2 = sW2; C3 = sW3; cstride = 32;   coff = 0; }
        else        { W1 = cW1; W2 = cW2; C3 = cW3; cstride = 1024; coff = (i - 1) * 32; }

        {
            int kl = tid & 63, jg = tid >> 6;
            #pragma unroll
            for (int jj = 0; jj < 8; ++jj) {
                int j = jg * 8 + jj;
                W1t[kl][j] = W1[j * 256 + kq * 64 + kl];
            }
        }
        float ct[32];
        {
            const float* src = C3 + (size_t)tid * cstride + coff;
            #pragma unroll
            for (int j4 = 0; j4 < 8; ++j4) {
                float4 v = *(const float4*)(src + j4 * 4);
                ct[j4 * 4 + 0] = v.x; ct[j4 * 4 + 1] = v.y;
                ct[j4 * 4 + 2] = v.z; ct[j4 * 4 + 3] = v.w;
            }
        }
        __syncthreads();

        for (int kg = 0; kg < 8; ++kg) {
            const int kbase = kq * 64 + kg * 8;
            short8 pk;
            #pragma unroll
            for (int q = 0; q < 8; ++q) {
                float a = 0.f;
                #pragma unroll
                for (int j4 = 0; j4 < 8; ++j4) {
                    float4 w = *(const float4*)&W1t[kg * 8 + q][j4 * 4];
                    a += w.x * ct[j4 * 4 + 0] + w.y * ct[j4 * 4 + 1]
                       + w.z * ct[j4 * 4 + 2] + w.w * ct[j4 * 4 + 3];
                }
                float m = a * W2[(size_t)(kbase + q) * 256 + tid];
                pk[q] = (short)f2bf(m);
            }
            *(short8*)(Mt + (size_t)i * 65536 + (size_t)tid * 256 + kbase) = pk;
        }
        return;
    }

    // ---------------- cW3 transpose-cast: cW3t[n][k] = bf16(cW3[k][n]) ----------------
    {
        const int pb = bid - (nfwd + 132);
        const int n0 = pb * 32;
        float (*fl)[33] = (float(*)[33])smem;   // [256][33]

        #pragma unroll
        for (int p = 0; p < 32; ++p) {
            int kk = p * 8 + (tid >> 5);
            int nn = tid & 31;
            fl[kk][nn] = cW3[(size_t)kk * 1024 + n0 + nn];
        }
        __syncthreads();

        const int nn   = tid >> 3;
        const int kseg = (tid & 7) * 32;
        #pragma unroll
        for (int c = 0; c < 4; ++c) {
            short8 v;
            #pragma unroll
            for (int u = 0; u < 8; ++u)
                v[u] = (short)f2bf(fl[kseg + c * 8 + u][nn]);
            *(short8*)(cW3t + (size_t)(n0 + nn) * 256 + kseg + c * 8) = v;
        }
    }
}

// ============================================================================
// KB v2: 37 MFMA jobs x 32 s-tiles, LDS-free (full co-residency for latency
// hiding via TLP). T2 contraction weights read from global in the epilogue.
//   jobs 0..32 : Z = T1[64x256] @ Mt_i ; out = sum_t T2[s,t]*Z[s,t]
//   jobs 33..36: cov quarter: C = H2c[64x256] @ cW3t_slice^T + cb3
// 256 threads (4 waves). Wave w: mh=w&1 (32-row half), nq=w>>1.
// ============================================================================
__global__ __launch_bounds__(256, 6) void kb_mfma(
    const unsigned short* __restrict__ T1s, const unsigned short* __restrict__ T2s,
    const unsigned short* __restrict__ T1c, const unsigned short* __restrict__ T2c,
    const unsigned short* __restrict__ H2c,
    const unsigned short* __restrict__ Mt,  const unsigned short* __restrict__ cW3t,
    const float* __restrict__ cb3,
    float* __restrict__ out_trace, float* __restrict__ out_cdiv,
    float* __restrict__ out_cov)
{
    const int stile = blockIdx.x;
    const int job   = blockIdx.y;
    const int sbase = stile * 64;
    const bool contr = (job < 33);

    const unsigned short* A  = contr ? (job == 0 ? T1s : T1c) : H2c;
    const unsigned short* Bm = contr ? (Mt + (size_t)job * 65536)
                                     : (cW3t + (size_t)(job - 33) * 65536);
    const unsigned short* T2 = (job == 0) ? T2s : T2c;

    __shared__ float red[2][64];

    const int tid  = threadIdx.x;
    const int w    = tid >> 6;
    const int lane = tid & 63;
    const int mh   = w & 1;
    const int nq   = w >> 1;
    const int g    = lane >> 4;
    const int r16  = lane & 15;

    float pp[2][4];
    #pragma unroll
    for (int mt = 0; mt < 2; ++mt)
        #pragma unroll
        for (int reg = 0; reg < 4; ++reg) pp[mt][reg] = 0.f;

    #pragma unroll
    for (int sec = 0; sec < 2; ++sec) {
        const int nbase = nq * 64 + sec * 128;
        floatx4 acc[2][4];
        #pragma unroll
        for (int mt = 0; mt < 2; ++mt)
            #pragma unroll
            for (int nt = 0; nt < 4; ++nt)
                acc[mt][nt] = (floatx4){0.f, 0.f, 0.f, 0.f};

        #pragma unroll
        for (int ks = 0; ks < 8; ++ks) {
            short8 af0 = *(const short8*)(A + (size_t)(sbase + mh * 32 + r16) * 256
                                            + ks * 32 + g * 8);
            short8 af1 = *(const short8*)(A + (size_t)(sbase + mh * 32 + 16 + r16) * 256
                                            + ks * 32 + g * 8);
            short8 bfr[4];
            #pragma unroll
            for (int nt = 0; nt < 4; ++nt)
                bfr[nt] = *(const short8*)(Bm + (size_t)(nbase + nt * 16 + r16) * 256
                                              + ks * 32 + g * 8);
            #pragma unroll
            for (int nt = 0; nt < 4; ++nt) {
                acc[0][nt] = __builtin_amdgcn_mfma_f32_16x16x32_bf16(af0, bfr[nt], acc[0][nt], 0, 0, 0);
                acc[1][nt] = __builtin_amdgcn_mfma_f32_16x16x32_bf16(af1, bfr[nt], acc[1][nt], 0, 0, 0);
            }
        }

        if (contr) {
            // epilogue contraction: T2 read directly from global (L2-hot)
            #pragma unroll
            for (int mt = 0; mt < 2; ++mt)
                #pragma unroll
                for (int nt = 0; nt < 4; ++nt)
                    #pragma unroll
                    for (int reg = 0; reg < 4; ++reg) {
                        int r = mh * 32 + mt * 16 + g * 4 + reg;
                        int t = nbase + nt * 16 + r16;
                        pp[mt][reg] += acc[mt][nt][reg]
                                     * bf2f(T2[(size_t)(sbase + r) * 256 + t]);
                    }
        } else {
            const int n0 = (job - 33) * 256;
            #pragma unroll
            for (int mt = 0; mt < 2; ++mt)
                #pragma unroll
                for (int nt = 0; nt < 4; ++nt) {
                    int n = nbase + nt * 16 + r16;
                    float bias = cb3[n0 + n];
                    #pragma unroll
                    for (int reg = 0; reg < 4; ++reg) {
                        int r = mh * 32 + mt * 16 + g * 4 + reg;
                        out_cov[(size_t)(sbase + r) * 1024 + n0 + n] = acc[mt][nt][reg] + bias;
                    }
                }
        }
    }

    if (contr) {
        #pragma unroll
        for (int mt = 0; mt < 2; ++mt)
            #pragma unroll
            for (int reg = 0; reg < 4; ++reg) {
                float v = pp[mt][reg];
                v += __shfl_xor(v, 1, 64);
                v += __shfl_xor(v, 2, 64);
                v += __shfl_xor(v, 4, 64);
                v += __shfl_xor(v, 8, 64);
                pp[mt][reg] = v;
            }
        if (r16 == 0) {
            #pragma unroll
            for (int mt = 0; mt < 2; ++mt)
                #pragma unroll
                for (int reg = 0; reg < 4; ++reg) {
                    int r = mh * 32 + mt * 16 + g * 4 + reg;
                    red[nq][r] = pp[mt][reg];
                }
        }
        __syncthreads();
        if (tid < 64) {
            float v = red[0][tid] + red[1][tid];
            int sg = sbase + tid;
            if (job == 0) out_trace[sg] = v;
            else          out_cdiv[(size_t)sg * Dd + (job - 1)] = v;
        }
    }
}

// ============================================================================
extern "C" void kernel_launch(void* const* d_in, const int* in_sizes, int n_in,
                              void* d_out, int out_size, void* d_ws, size_t ws_size,
                              hipStream_t stream) {
    const float* x   = (const float*)d_in[0];
    const float* sW1 = (const float*)d_in[1];
    const float* sb1 = (const float*)d_in[2];
    const float* sW2 = (const float*)d_in[3];
    const float* sb2 = (const float*)d_in[4];
    const float* sW3 = (const float*)d_in[5];
    const float* sb3 = (const float*)d_in[6];
    const float* cW1 = (const float*)d_in[7];
    const float* cb1 = (const float*)d_in[8];
    const float* cW2 = (const float*)d_in[9];
    const float* cb2 = (const float*)d_in[10];
    const float* cW3 = (const float*)d_in[11];
    const float* cb3 = (const float*)d_in[12];

    const int B = in_sizes[0] / Dd;   // 2048

    float* out       = (float*)d_out;
    float* out_score = out;                                  // [B,32]
    float* out_trace = out + (size_t)B * Dd;                 // [B]
    float* out_cov   = out_trace + B;                        // [B,32,32]
    float* out_cdiv  = out_cov + (size_t)B * Dd * Dd;        // [B,32]

    unsigned short* ws16 = (unsigned short*)d_ws;
    const size_t SZ = (size_t)B * 256;
    unsigned short* T1s  = ws16;
    unsigned short* T2s  = ws16 + SZ;
    unsigned short* T1c  = ws16 + 2 * SZ;
    unsigned short* T2c  = ws16 + 3 * SZ;
    unsigned short* H2c  = ws16 + 4 * SZ;
    unsigned short* Mt   = ws16 + 5 * SZ;                    // [33][256][256]
    unsigned short* cW3t = Mt + (size_t)33 * 65536;          // [1024][256]

    const int nfwd = B / 2;
    ka_fused<<<dim3(nfwd + 132 + 32), dim3(256), 0, stream>>>(
        x, sW1, sb1, sW2, sb2, sW3, sb3,
        cW1, cb1, cW2, cb2, cW3,
        out_score, T1s, T2s, T1c, T2c, H2c, Mt, cW3t, B);

    kb_mfma<<<dim3(B / 64, 37), dim3(256), 0, stream>>>(
        T1s, T2s, T1c, T2c, H2c, Mt, cW3t, cb3,
        out_trace, out_cdiv, out_cov);
}

// Round 5
// 162.459 us; speedup vs baseline: 1.2026x; 1.2026x over previous
//
#include <hip/hip_runtime.h>
#include <math.h>

#define Dd 32
#define Hh 256

using short8  = __attribute__((ext_vector_type(8))) short;
using floatx4 = __attribute__((ext_vector_type(4))) float;

__device__ inline unsigned short f2bf(float f) {
    union { float f; unsigned u; } v; v.f = f;
    unsigned r = (v.u + 0x7FFFu + ((v.u >> 16) & 1u)) >> 16;
    return (unsigned short)r;
}
__device__ inline float bf2f(unsigned short h) {
    union { unsigned u; float f; } v; v.u = ((unsigned)h) << 16;
    return v.f;
}

// ============================================================================
// KA: three partitions in one launch (grid.x = B/2 + 132 + 32):
//   [0, B/2):        forward layers 1-2 for one net x 4 samples (+ score head)
//   [B/2, B/2+132):  Mt precompute (kq 0..3, i 0..32)
//   [B/2+132, +32):  cW3 -> cW3t bf16 transpose-cast [1024][256]
// ============================================================================
__global__ __launch_bounds__(256) void ka_fused(
    const float* __restrict__ x,
    const float* __restrict__ sW1, const float* __restrict__ sb1,
    const float* __restrict__ sW2, const float* __restrict__ sb2,
    const float* __restrict__ sW3, const float* __restrict__ sb3,
    const float* __restrict__ cW1, const float* __restrict__ cb1,
    const float* __restrict__ cW2, const float* __restrict__ cb2,
    const float* __restrict__ cW3,
    float* __restrict__ out_score,
    unsigned short* __restrict__ T1s, unsigned short* __restrict__ T2s,
    unsigned short* __restrict__ T1c, unsigned short* __restrict__ T2c,
    unsigned short* __restrict__ H2c,
    unsigned short* __restrict__ Mt,  unsigned short* __restrict__ cW3t,
    int B)
{
    __shared__ char smem[33792];
    const int tid = threadIdx.x;
    const int bid = blockIdx.x;
    const int nfwd = B / 2;

    if (bid < nfwd) {
        // ---------------- forward: net = bid&1, samples sb..sb+3 ----------------
        const int net = bid & 1;
        const int sb  = (bid >> 1) * 4;
        float (*xT)[4]  = (float(*)[4])smem;            // [32][4]
        float (*h1t)[4] = (float(*)[4])(smem + 512);    // [256][4]
        float (*a2t)[4] = (float(*)[4])(smem + 4608);   // [256][4]

        if (tid < 128) {
            int s = tid >> 5, ii = tid & 31;
            xT[ii][s] = x[(sb + s) * Dd + ii];
        }
        __syncthreads();

        const float* W1 = net ? cW1 : sW1;  const float* b1 = net ? cb1 : sb1;
        const float* W2 = net ? cW2 : sW2;  const float* b2 = net ? cb2 : sb2;
        unsigned short* T1 = net ? T1c : T1s;
        unsigned short* T2 = net ? T2c : T2s;
        const int col = tid;

        float z[4];
        {
            float bb = b1[col];
            #pragma unroll
            for (int s = 0; s < 4; ++s) z[s] = bb;
        }
        #pragma unroll
        for (int ii = 0; ii < 32; ++ii) {
            float w = W1[ii * 256 + col];
            float4 xv = *(const float4*)xT[ii];
            z[0] += w * xv.x; z[1] += w * xv.y; z[2] += w * xv.z; z[3] += w * xv.w;
        }
        #pragma unroll
        for (int s = 0; s < 4; ++s) {
            float h = tanhf(z[s]);
            h1t[col][s] = h;
            T1[(size_t)(sb + s) * 256 + col] = f2bf(1.0f - h * h);
        }
        __syncthreads();

        {
            float bb = b2[col];
            #pragma unroll
            for (int s = 0; s < 4; ++s) z[s] = bb;
        }
        #pragma unroll 8
        for (int k = 0; k < 256; ++k) {
            float w = W2[k * 256 + col];
            float4 hv = *(const float4*)h1t[k];
            z[0] += w * hv.x; z[1] += w * hv.y; z[2] += w * hv.z; z[3] += w * hv.w;
        }
        #pragma unroll
        for (int s = 0; s < 4; ++s) {
            float h = tanhf(z[s]);
            T2[(size_t)(sb + s) * 256 + col] = f2bf(1.0f - h * h);
            if (net) H2c[(size_t)(sb + s) * 256 + col] = f2bf(h);
            else     a2t[col][s] = h;
        }
        __syncthreads();

        if (!net && tid < 128) {
            int m = tid & 31, s = tid >> 5;
            float zz = sb3[m];
            #pragma unroll 8
            for (int k = 0; k < 256; ++k)
                zz += a2t[k][s] * sW3[k * Dd + m];
            out_score[(size_t)(sb + s) * Dd + m] = zz;
        }
        return;
    }

    if (bid < nfwd + 132) {
        // ---------------- Mt precompute ----------------
        const int pb = bid - nfwd;
        const int kq = pb & 3;        // k quarter
        const int i  = pb >> 2;       // 0..32
        float (*W1t)[36] = (float(*)[36])smem;   // [64][36]

        const float *W1, *W2, *C3;
        int cstride, coff;
        if (i == 0) { W1 = sW1; W2 = sW2; C3 = sW3; cstride = 32;   coff = 0; }
        else        { W1 = cW1; W2 = cW2; C3 = cW3; cstride = 1024; coff = (i - 1) * 32; }

        {
            int kl = tid & 63, jg = tid >> 6;
            #pragma unroll
            for (int jj = 0; jj < 8; ++jj) {
                int j = jg * 8 + jj;
                W1t[kl][j] = W1[j * 256 + kq * 64 + kl];
            }
        }
        float ct[32];
        {
            const float* src = C3 + (size_t)tid * cstride + coff;
            #pragma unroll
            for (int j4 = 0; j4 < 8; ++j4) {
                float4 v = *(const float4*)(src + j4 * 4);
                ct[j4 * 4 + 0] = v.x; ct[j4 * 4 + 1] = v.y;
                ct[j4 * 4 + 2] = v.z; ct[j4 * 4 + 3] = v.w;
            }
        }
        __syncthreads();

        for (int kg = 0; kg < 8; ++kg) {
            const int kbase = kq * 64 + kg * 8;
            short8 pk;
            #pragma unroll
            for (int q = 0; q < 8; ++q) {
                float a = 0.f;
                #pragma unroll
                for (int j4 = 0; j4 < 8; ++j4) {
                    float4 w = *(const float4*)&W1t[kg * 8 + q][j4 * 4];
                    a += w.x * ct[j4 * 4 + 0] + w.y * ct[j4 * 4 + 1]
                       + w.z * ct[j4 * 4 + 2] + w.w * ct[j4 * 4 + 3];
                }
                float m = a * W2[(size_t)(kbase + q) * 256 + tid];
                pk[q] = (short)f2bf(m);
            }
            *(short8*)(Mt + (size_t)i * 65536 + (size_t)tid * 256 + kbase) = pk;
        }
        return;
    }

    // ---------------- cW3 transpose-cast: cW3t[n][k] = bf16(cW3[k][n]) ----------------
    {
        const int pb = bid - (nfwd + 132);
        const int n0 = pb * 32;
        float (*fl)[33] = (float(*)[33])smem;   // [256][33]

        #pragma unroll
        for (int p = 0; p < 32; ++p) {
            int kk = p * 8 + (tid >> 5);
            int nn = tid & 31;
            fl[kk][nn] = cW3[(size_t)kk * 1024 + n0 + nn];
        }
        __syncthreads();

        const int nn   = tid >> 3;
        const int kseg = (tid & 7) * 32;
        #pragma unroll
        for (int c = 0; c < 4; ++c) {
            short8 v;
            #pragma unroll
            for (int u = 0; u < 8; ++u)
                v[u] = (short)f2bf(fl[kseg + c * 8 + u][nn]);
            *(short8*)(cW3t + (size_t)(n0 + nn) * 256 + kseg + c * 8) = v;
        }
    }
}

// ============================================================================
// KB v3: software-pipelined MFMA with double-buffered LDS B-staging.
//   jobs 0..32 : Z = T1[64x256] @ Mt_i ; out = sum_t T2[s,t]*Z[s,t]
//   jobs 33..36: cov quarter: C = H2c[64x256] @ cW3t_slice^T + cb3
// 256 threads, 4 waves. Wave w: mh=w&1 (32-row half), nq=w>>1 (64-col group).
// K-loop: 16 steps = (sector 0..1) x (k-chunk 0..7); B chunk = 128 t-rows x
// 32 k staged in LDS (8 KB), double-buffered, register-prefetched.
// A-frags held in 64 VGPRs for the whole kernel. XOR-swizzled LDS slots
// give exactly 2-way bank aliasing on ds_read_b128 (free).
// ============================================================================
__global__ __launch_bounds__(256, 3) void kb_mfma(
    const unsigned short* __restrict__ T1s, const unsigned short* __restrict__ T2s,
    const unsigned short* __restrict__ T1c, const unsigned short* __restrict__ T2c,
    const unsigned short* __restrict__ H2c,
    const unsigned short* __restrict__ Mt,  const unsigned short* __restrict__ cW3t,
    const float* __restrict__ cb3,
    float* __restrict__ out_trace, float* __restrict__ out_cdiv,
    float* __restrict__ out_cov)
{
    const int stile = blockIdx.x;
    const int job   = blockIdx.y;
    const int sbase = stile * 64;
    const bool contr = (job < 33);

    const unsigned short* A  = contr ? (job == 0 ? T1s : T1c) : H2c;
    const unsigned short* Bm = contr ? (Mt + (size_t)job * 65536)
                                     : (cW3t + (size_t)(job - 33) * 65536);
    const unsigned short* T2 = (job == 0) ? T2s : T2c;

    __shared__ unsigned short Bs[2][128 * 32];   // 2 x 8 KB
    __shared__ float red[2][64];

    const int tid  = threadIdx.x;
    const int w    = tid >> 6;
    const int lane = tid & 63;
    const int mh   = w & 1;
    const int nq   = w >> 1;
    const int g    = lane >> 4;
    const int r16  = lane & 15;

    // ---- A-fragment preload (held in registers; reused every chunk & sector)
    short8 af[2][8];
    #pragma unroll
    for (int mt = 0; mt < 2; ++mt)
        #pragma unroll
        for (int c = 0; c < 8; ++c)
            af[mt][c] = *(const short8*)(A + (size_t)(sbase + mh * 32 + mt * 16 + r16) * 256
                                           + c * 32 + g * 8);

    // ---- staging ids: thread covers 32 B of one row per chunk
    const int tl   = tid >> 1;        // local row 0..127
    const int kseg = tid & 1;         // 32-B half of the 64-B k-slice
    const int slot0 = ((kseg * 2 + 0) + (tl >> 1)) & 3;
    const int slot1 = ((kseg * 2 + 1) + (tl >> 1)) & 3;

    // prefetch step 0
    short8 st0, st1;
    {
        const unsigned short* src = Bm + (size_t)tl * 256 + kseg * 16;
        st0 = *(const short8*)(src);
        st1 = *(const short8*)(src + 8);
    }

    float pp[2][4];
    #pragma unroll
    for (int mt = 0; mt < 2; ++mt)
        #pragma unroll
        for (int reg = 0; reg < 4; ++reg) pp[mt][reg] = 0.f;

    floatx4 acc[2][4];

    for (int idx = 0; idx < 16; ++idx) {
        const int buf = idx & 1;
        const int c   = idx & 7;
        const int sec = idx >> 3;

        // stage prefetched regs into LDS
        *(short8*)&Bs[buf][tl * 32 + slot0 * 8] = st0;
        *(short8*)&Bs[buf][tl * 32 + slot1 * 8] = st1;
        __syncthreads();

        // issue next chunk's global loads (in flight under the MFMAs)
        if (idx < 15) {
            const int ni = idx + 1;
            const unsigned short* src = Bm + (size_t)((ni >> 3) * 128 + tl) * 256
                                           + (ni & 7) * 32 + kseg * 16;
            st0 = *(const short8*)(src);
            st1 = *(const short8*)(src + 8);
        }

        if (c == 0) {
            #pragma unroll
            for (int mt = 0; mt < 2; ++mt)
                #pragma unroll
                for (int nt = 0; nt < 4; ++nt)
                    acc[mt][nt] = (floatx4){0.f, 0.f, 0.f, 0.f};
        }

        // MFMAs for this k-chunk: 4 nt tiles x 2 mt
        #pragma unroll
        for (int nt = 0; nt < 4; ++nt) {
            const int tloc = nq * 64 + nt * 16 + r16;
            short8 bfr = *(const short8*)&Bs[buf][tloc * 32 + ((g + (tloc >> 1)) & 3) * 8];
            acc[0][nt] = __builtin_amdgcn_mfma_f32_16x16x32_bf16(af[0][c], bfr, acc[0][nt], 0, 0, 0);
            acc[1][nt] = __builtin_amdgcn_mfma_f32_16x16x32_bf16(af[1][c], bfr, acc[1][nt], 0, 0, 0);
        }

        // sector epilogue
        if (c == 7) {
            const int nbase = sec * 128 + nq * 64;
            if (contr) {
                #pragma unroll
                for (int mt = 0; mt < 2; ++mt)
                    #pragma unroll
                    for (int nt = 0; nt < 4; ++nt)
                        #pragma unroll
                        for (int reg = 0; reg < 4; ++reg) {
                            int r = mh * 32 + mt * 16 + g * 4 + reg;
                            int t = nbase + nt * 16 + r16;
                            pp[mt][reg] += acc[mt][nt][reg]
                                         * bf2f(T2[(size_t)(sbase + r) * 256 + t]);
                        }
            } else {
                const int n0 = (job - 33) * 256;
                #pragma unroll
                for (int mt = 0; mt < 2; ++mt)
                    #pragma unroll
                    for (int nt = 0; nt < 4; ++nt) {
                        int n = nbase + nt * 16 + r16;
                        float bias = cb3[n0 + n];
                        #pragma unroll
                        for (int reg = 0; reg < 4; ++reg) {
                            int r = mh * 32 + mt * 16 + g * 4 + reg;
                            out_cov[(size_t)(sbase + r) * 1024 + n0 + n] = acc[mt][nt][reg] + bias;
                        }
                    }
            }
        }
    }

    if (contr) {
        #pragma unroll
        for (int mt = 0; mt < 2; ++mt)
            #pragma unroll
            for (int reg = 0; reg < 4; ++reg) {
                float v = pp[mt][reg];
                v += __shfl_xor(v, 1, 64);
                v += __shfl_xor(v, 2, 64);
                v += __shfl_xor(v, 4, 64);
                v += __shfl_xor(v, 8, 64);
                pp[mt][reg] = v;
            }
        if (r16 == 0) {
            #pragma unroll
            for (int mt = 0; mt < 2; ++mt)
                #pragma unroll
                for (int reg = 0; reg < 4; ++reg) {
                    int r = mh * 32 + mt * 16 + g * 4 + reg;
                    red[nq][r] = pp[mt][reg];
                }
        }
        __syncthreads();
        if (tid < 64) {
            float v = red[0][tid] + red[1][tid];
            int sg = sbase + tid;
            if (job == 0) out_trace[sg] = v;
            else          out_cdiv[(size_t)sg * Dd + (job - 1)] = v;
        }
    }
}

// ============================================================================
extern "C" void kernel_launch(void* const* d_in, const int* in_sizes, int n_in,
                              void* d_out, int out_size, void* d_ws, size_t ws_size,
                              hipStream_t stream) {
    const float* x   = (const float*)d_in[0];
    const float* sW1 = (const float*)d_in[1];
    const float* sb1 = (const float*)d_in[2];
    const float* sW2 = (const float*)d_in[3];
    const float* sb2 = (const float*)d_in[4];
    const float* sW3 = (const float*)d_in[5];
    const float* sb3 = (const float*)d_in[6];
    const float* cW1 = (const float*)d_in[7];
    const float* cb1 = (const float*)d_in[8];
    const float* cW2 = (const float*)d_in[9];
    const float* cb2 = (const float*)d_in[10];
    const float* cW3 = (const float*)d_in[11];
    const float* cb3 = (const float*)d_in[12];

    const int B = in_sizes[0] / Dd;   // 2048

    float* out       = (float*)d_out;
    float* out_score = out;                                  // [B,32]
    float* out_trace = out + (size_t)B * Dd;                 // [B]
    float* out_cov   = out_trace + B;                        // [B,32,32]
    float* out_cdiv  = out_cov + (size_t)B * Dd * Dd;        // [B,32]

    unsigned short* ws16 = (unsigned short*)d_ws;
    const size_t SZ = (size_t)B * 256;
    unsigned short* T1s  = ws16;
    unsigned short* T2s  = ws16 + SZ;
    unsigned short* T1c  = ws16 + 2 * SZ;
    unsigned short* T2c  = ws16 + 3 * SZ;
    unsigned short* H2c  = ws16 + 4 * SZ;
    unsigned short* Mt   = ws16 + 5 * SZ;                    // [33][256][256]
    unsigned short* cW3t = Mt + (size_t)33 * 65536;          // [1024][256]

    const int nfwd = B / 2;
    ka_fused<<<dim3(nfwd + 132 + 32), dim3(256), 0, stream>>>(
        x, sW1, sb1, sW2, sb2, sW3, sb3,
        cW1, cb1, cW2, cb2, cW3,
        out_score, T1s, T2s, T1c, T2c, H2c, Mt, cW3t, B);

    kb_mfma<<<dim3(B / 64, 37), dim3(256), 0, stream>>>(
        T1s, T2s, T1c, T2c, H2c, Mt, cW3t, cb3,
        out_trace, out_cdiv, out_cov);
}

// Round 6
// 144.625 us; speedup vs baseline: 1.3509x; 1.1233x over previous
//
#include <hip/hip_runtime.h>
#include <math.h>

#define Dd 32
#define Hh 256

using short8  = __attribute__((ext_vector_type(8))) short;
using floatx4 = __attribute__((ext_vector_type(4))) float;

__device__ inline unsigned short f2bf(float f) {
    union { float f; unsigned u; } v; v.f = f;
    unsigned r = (v.u + 0x7FFFu + ((v.u >> 16) & 1u)) >> 16;
    return (unsigned short)r;
}
__device__ inline float bf2f(unsigned short h) {
    union { unsigned u; float f; } v; v.u = ((unsigned)h) << 16;
    return v.f;
}

// ============================================================================
// K0: prep. grid.x = 132 (Mt) + 32 (cW3t) + 8 (sW2t) + 8 (cW2t) + 1 (sW3t)
//           + 2 (W1t) = 183 blocks, 256 threads. smem 9216 B.
//   Mt[i][t][k]: i=0: sW2[k,t]*sum_m sW1[m,k]sW3[t,m];
//                i>=1: cW2[k,t]*sum_j cW1[j,k]cW3[t,(i-1)*32+j]   (bf16)
//   Transpose-casts to bf16 [n][k=256] row-major: cW3t, sW2t, cW2t, sW3t.
//   W1t[net][n][k=32] bf16.
// ============================================================================
__global__ __launch_bounds__(256) void k0_prep(
    const float* __restrict__ sW1, const float* __restrict__ sW2, const float* __restrict__ sW3,
    const float* __restrict__ cW1, const float* __restrict__ cW2, const float* __restrict__ cW3,
    unsigned short* __restrict__ Mt,   unsigned short* __restrict__ cW3t,
    unsigned short* __restrict__ sW2t, unsigned short* __restrict__ cW2t,
    unsigned short* __restrict__ sW3t,
    unsigned short* __restrict__ W1ts, unsigned short* __restrict__ W1tc)
{
    __shared__ char smem[9216];
    const int tid = threadIdx.x;
    const int bid = blockIdx.x;

    if (bid < 132) {
        // ---------------- Mt precompute ----------------
        const int kq = bid & 3;
        const int i  = bid >> 2;
        float (*W1t)[36] = (float(*)[36])smem;   // [64][36]

        const float *W1, *W2, *C3;
        int cstride, coff;
        if (i == 0) { W1 = sW1; W2 = sW2; C3 = sW3; cstride = 32;   coff = 0; }
        else        { W1 = cW1; W2 = cW2; C3 = cW3; cstride = 1024; coff = (i - 1) * 32; }

        {
            int kl = tid & 63, jg = tid >> 6;
            #pragma unroll
            for (int jj = 0; jj < 8; ++jj) {
                int j = jg * 8 + jj;
                W1t[kl][j] = W1[j * 256 + kq * 64 + kl];
            }
        }
        float ct[32];
        {
            const float* src = C3 + (size_t)tid * cstride + coff;
            #pragma unroll
            for (int j4 = 0; j4 < 8; ++j4) {
                float4 v = *(const float4*)(src + j4 * 4);
                ct[j4 * 4 + 0] = v.x; ct[j4 * 4 + 1] = v.y;
                ct[j4 * 4 + 2] = v.z; ct[j4 * 4 + 3] = v.w;
            }
        }
        __syncthreads();

        for (int kg = 0; kg < 8; ++kg) {
            const int kbase = kq * 64 + kg * 8;
            short8 pk;
            #pragma unroll
            for (int q = 0; q < 8; ++q) {
                float a = 0.f;
                #pragma unroll
                for (int j4 = 0; j4 < 8; ++j4) {
                    float4 w = *(const float4*)&W1t[kg * 8 + q][j4 * 4];
                    a += w.x * ct[j4 * 4 + 0] + w.y * ct[j4 * 4 + 1]
                       + w.z * ct[j4 * 4 + 2] + w.w * ct[j4 * 4 + 3];
                }
                float m = a * W2[(size_t)(kbase + q) * 256 + tid];
                pk[q] = (short)f2bf(m);
            }
            *(short8*)(Mt + (size_t)i * 65536 + (size_t)tid * 256 + kbase) = pk;
        }
        return;
    }

    if (bid < 181) {
        // ---------------- generic transpose-cast: dst[n][k] = bf16(src[k][n]) ----------------
        const float* src; unsigned short* dst; int stride, n0;
        if (bid < 164)      { src = cW3; dst = cW3t; stride = 1024; n0 = (bid - 132) * 32; }
        else if (bid < 172) { src = sW2; dst = sW2t; stride = 256;  n0 = (bid - 164) * 32; }
        else if (bid < 180) { src = cW2; dst = cW2t; stride = 256;  n0 = (bid - 172) * 32; }
        else                { src = sW3; dst = sW3t; stride = 32;   n0 = 0; }

        float (*fl)[33] = (float(*)[33])smem;    // [64][33]
        const int nn  = tid & 31, kg = tid >> 5;     // read ids
        const int nn2 = tid >> 3, ks = (tid & 7) * 8; // write ids

        for (int p = 0; p < 4; ++p) {
            if (p) __syncthreads();
            #pragma unroll
            for (int j = 0; j < 8; ++j) {
                int kk = kg * 8 + j;
                fl[kk][nn] = src[(size_t)(p * 64 + kk) * stride + n0 + nn];
            }
            __syncthreads();
            short8 v;
            #pragma unroll
            for (int j = 0; j < 8; ++j) v[j] = (short)f2bf(fl[ks + j][nn2]);
            *(short8*)(dst + (size_t)(n0 + nn2) * 256 + p * 64 + ks) = v;
        }
        return;
    }

    // ---------------- W1t: [256 n][32 k] bf16, W1t[n][k] = W1[k][n] ----------------
    {
        const float* W1 = (bid == 181) ? sW1 : cW1;
        unsigned short* dst = (bid == 181) ? W1ts : W1tc;
        const int n = tid;
        #pragma unroll
        for (int c = 0; c < 4; ++c) {
            short8 v;
            #pragma unroll
            for (int j = 0; j < 8; ++j)
                v[j] = (short)f2bf(W1[(size_t)(c * 8 + j) * 256 + n]);
            *(short8*)(dst + (size_t)n * 32 + c * 8) = v;
        }
    }
}

// ============================================================================
// KA-MFMA: forward via bf16 MFMA. grid (128 sample-tiles, 2 nets), 256 thr.
//   layer1: z1[16s][256n] = x[16][32] @ W1   (1 k-step; B = W1t rows)
//   layer2 (transposed): z2^T[256c][16s] = W2t @ h1^T
//       A = W2t[c][k] (global, L2-hot), B = h1[s][k] (LDS, staged layer1)
//   heads: score net -> score^T = sW3t @ h2^T (2 m-tiles); cov -> H2c only.
// Writes T1/T2 (bf16 dtanh), H2c, out_score. KB consumes them unchanged.
// ============================================================================
__global__ __launch_bounds__(256) void ka_mfma(
    const float* __restrict__ x,
    const unsigned short* __restrict__ W1ts, const unsigned short* __restrict__ W1tc,
    const unsigned short* __restrict__ sW2t, const unsigned short* __restrict__ cW2t,
    const unsigned short* __restrict__ sW3t,
    const float* __restrict__ sb1, const float* __restrict__ sb2, const float* __restrict__ sb3,
    const float* __restrict__ cb1, const float* __restrict__ cb2,
    float* __restrict__ out_score,
    unsigned short* __restrict__ T1s, unsigned short* __restrict__ T2s,
    unsigned short* __restrict__ T1c, unsigned short* __restrict__ T2c,
    unsigned short* __restrict__ H2c)
{
    const int sb  = blockIdx.x * 16;
    const int net = blockIdx.y;

    const unsigned short* W1t = net ? W1tc : W1ts;
    const unsigned short* W2t = net ? cW2t : sW2t;
    const float* b1 = net ? cb1 : sb1;
    const float* b2 = net ? cb2 : sb2;
    unsigned short* T1 = net ? T1c : T1s;
    unsigned short* T2 = net ? T2c : T2s;

    __shared__ unsigned short hB[16][264];   // h (B^T layout: [sample][k]), padded

    const int tid  = threadIdx.x;
    const int w    = tid >> 6;
    const int lane = tid & 63;
    const int g    = lane >> 4;
    const int r16  = lane & 15;

    // ---- A-frag: x samples, cast to bf16 inline (k = 32 = one MFMA step)
    short8 ax;
    {
        const float* xs = x + (size_t)(sb + r16) * 32 + g * 8;
        float4 a = *(const float4*)xs;
        float4 b = *(const float4*)(xs + 4);
        ax[0] = (short)f2bf(a.x); ax[1] = (short)f2bf(a.y);
        ax[2] = (short)f2bf(a.z); ax[3] = (short)f2bf(a.w);
        ax[4] = (short)f2bf(b.x); ax[5] = (short)f2bf(b.y);
        ax[6] = (short)f2bf(b.z); ax[7] = (short)f2bf(b.w);
    }

    // ---- layer 1: wave w covers n-tiles w*4 .. w*4+3
    #pragma unroll
    for (int nt = 0; nt < 4; ++nt) {
        const int nb = w * 64 + nt * 16;          // tile base col
        short8 bf = *(const short8*)(W1t + (size_t)(nb + r16) * 32 + g * 8);
        floatx4 acc = (floatx4){0.f, 0.f, 0.f, 0.f};
        acc = __builtin_amdgcn_mfma_f32_16x16x32_bf16(ax, bf, acc, 0, 0, 0);
        const float bias = b1[nb + r16];
        #pragma unroll
        for (int reg = 0; reg < 4; ++reg) {
            float h = tanhf(acc[reg] + bias);
            int m = g * 4 + reg;                  // local sample
            hB[m][nb + r16] = f2bf(h);
            T1[(size_t)(sb + m) * 256 + nb + r16] = f2bf(1.0f - h * h);
        }
    }
    __syncthreads();

    // ---- layer 2 (z2^T): B-frags (h1) hoisted, reused across 4 m-tiles
    short8 bfr[8];
    #pragma unroll
    for (int ks = 0; ks < 8; ++ks)
        bfr[ks] = *(const short8*)&hB[r16][ks * 32 + g * 8];

    unsigned short h2st[4][4];                    // stash h2 (score net staging)
    #pragma unroll
    for (int mt = 0; mt < 4; ++mt) {
        const int cb = w * 64 + mt * 16;          // col2 tile base
        floatx4 acc = (floatx4){0.f, 0.f, 0.f, 0.f};
        #pragma unroll
        for (int ks = 0; ks < 8; ++ks) {
            short8 af = *(const short8*)(W2t + (size_t)(cb + r16) * 256 + ks * 32 + g * 8);
            acc = __builtin_amdgcn_mfma_f32_16x16x32_bf16(af, bfr[ks], acc, 0, 0, 0);
        }
        #pragma unroll
        for (int reg = 0; reg < 4; ++reg) {
            const int c2 = cb + g * 4 + reg;      // output col (row of z2^T)
            float h = tanhf(acc[reg] + b2[c2]);
            unsigned short hb = f2bf(h);
            T2[(size_t)(sb + r16) * 256 + c2] = f2bf(1.0f - h * h);
            if (net) H2c[(size_t)(sb + r16) * 256 + c2] = hb;
            h2st[mt][reg] = hb;
        }
    }

    if (!net) {
        // ---- score head: restage h2 into hB, then 2 m-tile MFMA
        __syncthreads();                          // all reads of h1 done
        #pragma unroll
        for (int mt = 0; mt < 4; ++mt)
            #pragma unroll
            for (int reg = 0; reg < 4; ++reg)
                hB[r16][w * 64 + mt * 16 + g * 4 + reg] = h2st[mt][reg];
        __syncthreads();

        if (w < 2) {
            floatx4 acc = (floatx4){0.f, 0.f, 0.f, 0.f};
            #pragma unroll
            for (int ks = 0; ks < 8; ++ks) {
                short8 af = *(const short8*)(sW3t + (size_t)(w * 16 + r16) * 256 + ks * 32 + g * 8);
                short8 bf = *(const short8*)&hB[r16][ks * 32 + g * 8];
                acc = __builtin_amdgcn_mfma_f32_16x16x32_bf16(af, bf, acc, 0, 0, 0);
            }
            #pragma unroll
            for (int reg = 0; reg < 4; ++reg) {
                const int m = w * 16 + g * 4 + reg;
                out_score[(size_t)(sb + r16) * 32 + m] = acc[reg] + sb3[m];
            }
        }
    }
}

// ============================================================================
// KB v3 (unchanged from R5): software-pipelined MFMA, double-buffered LDS B.
// ============================================================================
__global__ __launch_bounds__(256, 3) void kb_mfma(
    const unsigned short* __restrict__ T1s, const unsigned short* __restrict__ T2s,
    const unsigned short* __restrict__ T1c, const unsigned short* __restrict__ T2c,
    const unsigned short* __restrict__ H2c,
    const unsigned short* __restrict__ Mt,  const unsigned short* __restrict__ cW3t,
    const float* __restrict__ cb3,
    float* __restrict__ out_trace, float* __restrict__ out_cdiv,
    float* __restrict__ out_cov)
{
    const int stile = blockIdx.x;
    const int job   = blockIdx.y;
    const int sbase = stile * 64;
    const bool contr = (job < 33);

    const unsigned short* A  = contr ? (job == 0 ? T1s : T1c) : H2c;
    const unsigned short* Bm = contr ? (Mt + (size_t)job * 65536)
                                     : (cW3t + (size_t)(job - 33) * 65536);
    const unsigned short* T2 = (job == 0) ? T2s : T2c;

    __shared__ unsigned short Bs[2][128 * 32];
    __shared__ float red[2][64];

    const int tid  = threadIdx.x;
    const int w    = tid >> 6;
    const int lane = tid & 63;
    const int mh   = w & 1;
    const int nq   = w >> 1;
    const int g    = lane >> 4;
    const int r16  = lane & 15;

    short8 af[2][8];
    #pragma unroll
    for (int mt = 0; mt < 2; ++mt)
        #pragma unroll
        for (int c = 0; c < 8; ++c)
            af[mt][c] = *(const short8*)(A + (size_t)(sbase + mh * 32 + mt * 16 + r16) * 256
                                           + c * 32 + g * 8);

    const int tl   = tid >> 1;
    const int kseg = tid & 1;
    const int slot0 = ((kseg * 2 + 0) + (tl >> 1)) & 3;
    const int slot1 = ((kseg * 2 + 1) + (tl >> 1)) & 3;

    short8 st0, st1;
    {
        const unsigned short* src = Bm + (size_t)tl * 256 + kseg * 16;
        st0 = *(const short8*)(src);
        st1 = *(const short8*)(src + 8);
    }

    float pp[2][4];
    #pragma unroll
    for (int mt = 0; mt < 2; ++mt)
        #pragma unroll
        for (int reg = 0; reg < 4; ++reg) pp[mt][reg] = 0.f;

    floatx4 acc[2][4];

    for (int idx = 0; idx < 16; ++idx) {
        const int buf = idx & 1;
        const int c   = idx & 7;
        const int sec = idx >> 3;

        *(short8*)&Bs[buf][tl * 32 + slot0 * 8] = st0;
        *(short8*)&Bs[buf][tl * 32 + slot1 * 8] = st1;
        __syncthreads();

        if (idx < 15) {
            const int ni = idx + 1;
            const unsigned short* src = Bm + (size_t)((ni >> 3) * 128 + tl) * 256
                                           + (ni & 7) * 32 + kseg * 16;
            st0 = *(const short8*)(src);
            st1 = *(const short8*)(src + 8);
        }

        if (c == 0) {
            #pragma unroll
            for (int mt = 0; mt < 2; ++mt)
                #pragma unroll
                for (int nt = 0; nt < 4; ++nt)
                    acc[mt][nt] = (floatx4){0.f, 0.f, 0.f, 0.f};
        }

        #pragma unroll
        for (int nt = 0; nt < 4; ++nt) {
            const int tloc = nq * 64 + nt * 16 + r16;
            short8 bfr = *(const short8*)&Bs[buf][tloc * 32 + ((g + (tloc >> 1)) & 3) * 8];
            acc[0][nt] = __builtin_amdgcn_mfma_f32_16x16x32_bf16(af[0][c], bfr, acc[0][nt], 0, 0, 0);
            acc[1][nt] = __builtin_amdgcn_mfma_f32_16x16x32_bf16(af[1][c], bfr, acc[1][nt], 0, 0, 0);
        }

        if (c == 7) {
            const int nbase = sec * 128 + nq * 64;
            if (contr) {
                #pragma unroll
                for (int mt = 0; mt < 2; ++mt)
                    #pragma unroll
                    for (int nt = 0; nt < 4; ++nt)
                        #pragma unroll
                        for (int reg = 0; reg < 4; ++reg) {
                            int r = mh * 32 + mt * 16 + g * 4 + reg;
                            int t = nbase + nt * 16 + r16;
                            pp[mt][reg] += acc[mt][nt][reg]
                                         * bf2f(T2[(size_t)(sbase + r) * 256 + t]);
                        }
            } else {
                const int n0 = (job - 33) * 256;
                #pragma unroll
                for (int mt = 0; mt < 2; ++mt)
                    #pragma unroll
                    for (int nt = 0; nt < 4; ++nt) {
                        int n = nbase + nt * 16 + r16;
                        float bias = cb3[n0 + n];
                        #pragma unroll
                        for (int reg = 0; reg < 4; ++reg) {
                            int r = mh * 32 + mt * 16 + g * 4 + reg;
                            out_cov[(size_t)(sbase + r) * 1024 + n0 + n] = acc[mt][nt][reg] + bias;
                        }
                    }
            }
        }
    }

    if (contr) {
        #pragma unroll
        for (int mt = 0; mt < 2; ++mt)
            #pragma unroll
            for (int reg = 0; reg < 4; ++reg) {
                float v = pp[mt][reg];
                v += __shfl_xor(v, 1, 64);
                v += __shfl_xor(v, 2, 64);
                v += __shfl_xor(v, 4, 64);
                v += __shfl_xor(v, 8, 64);
                pp[mt][reg] = v;
            }
        if (r16 == 0) {
            #pragma unroll
            for (int mt = 0; mt < 2; ++mt)
                #pragma unroll
                for (int reg = 0; reg < 4; ++reg) {
                    int r = mh * 32 + mt * 16 + g * 4 + reg;
                    red[nq][r] = pp[mt][reg];
                }
        }
        __syncthreads();
        if (tid < 64) {
            float v = red[0][tid] + red[1][tid];
            int sg = sbase + tid;
            if (job == 0) out_trace[sg] = v;
            else          out_cdiv[(size_t)sg * Dd + (job - 1)] = v;
        }
    }
}

// ============================================================================
extern "C" void kernel_launch(void* const* d_in, const int* in_sizes, int n_in,
                              void* d_out, int out_size, void* d_ws, size_t ws_size,
                              hipStream_t stream) {
    const float* x   = (const float*)d_in[0];
    const float* sW1 = (const float*)d_in[1];
    const float* sb1 = (const float*)d_in[2];
    const float* sW2 = (const float*)d_in[3];
    const float* sb2 = (const float*)d_in[4];
    const float* sW3 = (const float*)d_in[5];
    const float* sb3 = (const float*)d_in[6];
    const float* cW1 = (const float*)d_in[7];
    const float* cb1 = (const float*)d_in[8];
    const float* cW2 = (const float*)d_in[9];
    const float* cb2 = (const float*)d_in[10];
    const float* cW3 = (const float*)d_in[11];
    const float* cb3 = (const float*)d_in[12];

    const int B = in_sizes[0] / Dd;   // 2048

    float* out       = (float*)d_out;
    float* out_score = out;                                  // [B,32]
    float* out_trace = out + (size_t)B * Dd;                 // [B]
    float* out_cov   = out_trace + B;                        // [B,32,32]
    float* out_cdiv  = out_cov + (size_t)B * Dd * Dd;        // [B,32]

    unsigned short* ws16 = (unsigned short*)d_ws;
    const size_t SZ = (size_t)B * 256;
    unsigned short* T1s  = ws16;
    unsigned short* T2s  = ws16 + SZ;
    unsigned short* T1c  = ws16 + 2 * SZ;
    unsigned short* T2c  = ws16 + 3 * SZ;
    unsigned short* H2c  = ws16 + 4 * SZ;
    unsigned short* Mt   = ws16 + 5 * SZ;                    // [33][256][256]
    unsigned short* cW3t = Mt + (size_t)33 * 65536;          // [1024][256]
    unsigned short* sW2t = cW3t + (size_t)1024 * 256;        // [256][256]
    unsigned short* cW2t = sW2t + (size_t)256 * 256;
    unsigned short* sW3t = cW2t + (size_t)256 * 256;         // [32][256]
    unsigned short* W1ts = sW3t + (size_t)32 * 256;          // [256][32]
    unsigned short* W1tc = W1ts + (size_t)256 * 32;

    k0_prep<<<dim3(183), dim3(256), 0, stream>>>(
        sW1, sW2, sW3, cW1, cW2, cW3,
        Mt, cW3t, sW2t, cW2t, sW3t, W1ts, W1tc);

    ka_mfma<<<dim3(B / 16, 2), dim3(256), 0, stream>>>(
        x, W1ts, W1tc, sW2t, cW2t, sW3t,
        sb1, sb2, sb3, cb1, cb2,
        out_score, T1s, T2s, T1c, T2c, H2c);

    kb_mfma<<<dim3(B / 64, 37), dim3(256), 0, stream>>>(
        T1s, T2s, T1c, T2c, H2c, Mt, cW3t, cb3,
        out_trace, out_cdiv, out_cov);
}